// Round 1
// 270.900 us; speedup vs baseline: 1.0392x; 1.0392x over previous
//
#include <hip/hip_runtime.h>
#include <hip/hip_bf16.h>

#define NNODES 100000
#define NEDGES 1600000
#define IN_CH 128
#define HID 64
#define NC 40
#define NPAD 100352   // NNODES padded to multiple of 256
#define NBUK 196      // ceil(100000 / 512) dst-buckets of 512 nodes
#define CAP 9216      // per-bucket tmp capacity (mean 8192, sigma ~90 -> 11 sigma)
#define BCHUNK 4096
#define NBIN 391      // ceil(NEDGES / BCHUNK)

typedef unsigned short ushort_t;
typedef unsigned int uint_t;
typedef __attribute__((ext_vector_type(8))) short short8;
typedef __attribute__((ext_vector_type(4))) float floatx4;

__device__ __forceinline__ float bf2f(ushort_t u) {
    union { unsigned int i; float f; } t;
    t.i = ((unsigned int)u) << 16;
    return t.f;
}
__device__ __forceinline__ ushort_t f2bf(float f) {
    union { float ff; unsigned int i; } t;
    t.ff = f;
    unsigned int r = t.i + 0x7fff + ((t.i >> 16) & 1);  // RNE
    return (ushort_t)(r >> 16);
}
// unpack packed bf16x2
__device__ __forceinline__ float2 unpk(uint_t p) {
    union { unsigned int i; float f; } a, b;
    a.i = p << 16;
    b.i = p & 0xffff0000u;
    return make_float2(a.f, b.f);
}

// ---- gcur[b] = b*CAP ----
__global__ void k_ginit(int* __restrict__ gcur) {
    int b = threadIdx.x;
    if (b < NBUK) gcur[b] = b * CAP;
}

// ---- bin edges into bucket-major tmp; entry: src(17b) | local_d(9b)<<17 ----
__global__ __launch_bounds__(256) void k_bin0(
    const int* __restrict__ srcs, const int* __restrict__ dsts,
    int* __restrict__ gcur, uint_t* __restrict__ tmp, int e)
{
    __shared__ uint_t pk[BCHUNK];    // 16 KB
    __shared__ ushort_t bk[BCHUNK];  // 8 KB
    __shared__ int hist[NBUK];
    __shared__ int base[NBUK];
    int t = threadIdx.x;
    int begin = blockIdx.x * BCHUNK;
    int cnt = e - begin; if (cnt > BCHUNK) cnt = BCHUNK;

    for (int i = t; i < NBUK; i += 256) hist[i] = 0;
    __syncthreads();
    for (int j = t; j < cnt; j += 256) {
        int d = dsts[begin + j];
        int s = srcs[begin + j];
        int b = d >> 9;
        pk[j] = (uint_t)s | ((uint_t)(d & 511) << 17);
        bk[j] = (ushort_t)b;
        atomicAdd(&hist[b], 1);
    }
    __syncthreads();
    for (int i = t; i < NBUK; i += 256) {
        base[i] = atomicAdd(&gcur[i], hist[i]);  // reserve segment in bucket i
        hist[i] = 0;                             // reuse as local rank cursor
    }
    __syncthreads();
    for (int j = t; j < cnt; j += 256) {
        int b = bk[j];
        int r = atomicAdd(&hist[b], 1);
        int pos = base[b] + r;
        if (pos < (b + 1) * CAP) tmp[pos] = pk[j];  // burst writes; guard vs overflow
    }
}

// ---- exclusive scan of bucket totals -> bbase[0..NBUK], single block ----
__global__ __launch_bounds__(256) void k_bbase(const int* __restrict__ gcur,
                                               int* __restrict__ bbase, int e) {
    __shared__ int s[256];
    int t = threadIdx.x;
    int c = (t < NBUK) ? (gcur[t] - t * CAP) : 0;
    s[t] = c;
    __syncthreads();
    for (int off = 1; off < 256; off <<= 1) {
        int v = (t >= off) ? s[t - off] : 0;
        __syncthreads();
        s[t] += v;
        __syncthreads();
    }
    if (t < NBUK) bbase[t] = s[t] - c;
    if (t == 0) bbase[NBUK] = e;
}

// ---- per-bucket: count per node (LDS), scan 512, write row_start + dinv ----
__global__ __launch_bounds__(256) void k_sort_a(
    const uint_t* __restrict__ tmp, const int* __restrict__ gcur,
    const int* __restrict__ bbase, int* __restrict__ row_start,
    float* __restrict__ dinv, int n, int e)
{
    __shared__ int cnt[512];
    __shared__ int sc[512];
    int t = threadIdx.x;
    int b = blockIdx.x;
    int d0 = b << 9;
    int total = gcur[b] - b * CAP;
    cnt[t] = 0; cnt[t + 256] = 0;
    __syncthreads();
    const uint_t* seg = tmp + b * CAP;
    for (int j = t; j < total; j += 256)
        atomicAdd(&cnt[seg[j] >> 17], 1);
    __syncthreads();
    sc[t] = cnt[t]; sc[t + 256] = cnt[t + 256];
    __syncthreads();
    for (int off = 1; off < 512; off <<= 1) {
        int v0 = (t >= off) ? sc[t - off] : 0;
        int i1 = t + 256;
        int v1 = (i1 >= off) ? sc[i1 - off] : 0;
        __syncthreads();
        sc[t] += v0; sc[i1] += v1;
        __syncthreads();
    }
    int gb = bbase[b];
#pragma unroll
    for (int q = 0; q < 2; ++q) {
        int i = t + q * 256;
        int node = d0 + i;
        if (node < n) {
            row_start[node] = gb + sc[i] - cnt[i];
            dinv[node] = rsqrtf((float)cnt[i] + 1.0f);
        }
    }
    if (b == NBUK - 1 && t == 0) row_start[n] = e;
}

// ---- per-bucket: scatter src indices to final CSR order (dinv folded into hw rows) ----
__global__ __launch_bounds__(256) void k_sort_b(
    const uint_t* __restrict__ tmp, const int* __restrict__ gcur,
    const int* __restrict__ row_start, uint_t* __restrict__ es, int n)
{
    __shared__ int cur[512];
    int t = threadIdx.x;
    int b = blockIdx.x;
    int d0 = b << 9;
    int total = gcur[b] - b * CAP;
#pragma unroll
    for (int q = 0; q < 2; ++q) {
        int i = t + q * 256;
        int node = d0 + i;
        cur[i] = (node < n) ? row_start[node] : 0;
    }
    __syncthreads();
    const uint_t* seg = tmp + b * CAP;
    for (int j = t; j < total; j += 256) {
        uint_t p = seg[j];                 // coalesced
        int ld = (int)(p >> 17);
        int pos = atomicAdd(&cur[ld], 1);
        es[pos] = p & 0x1FFFFu;            // src only; weight folded into hw rows
    }
}

// ---- pre-swizzle W1 (f32) into bf16 B-fragment order ----
__global__ void k_prepw(const float* __restrict__ W1, ushort_t* __restrict__ Wp) {
    int i = blockIdx.x * 256 + threadIdx.x;
    if (i >= IN_CH * HID) return;
    int j = i & 7;
    int m = (i >> 3) & 15;
    int ct = (i >> 7) & 3;
    int quad = (i >> 9) & 3;
    int kc = i >> 11;
    int k = kc * 32 + quad * 8 + j;
    int c = ct * 16 + m;
    Wp[i] = f2bf(W1[k * HID + c]);
}

// ---- GEMM1: hw1 = bf16(dinv * (x @ W1)) via MFMA; row n = zero sentinel ----
__global__ __launch_bounds__(256) void k_gemm1(
    const float* __restrict__ x, const ushort_t* __restrict__ Wp,
    const float* __restrict__ dinv, ushort_t* __restrict__ hw1, int n)
{
    int wave = threadIdx.x >> 6;
    int lane = threadIdx.x & 63;
    int m = lane & 15;
    int quad = lane >> 4;
    int row = blockIdx.x * 64 + wave * 16 + m;
    int rowc = row < n ? row : (n - 1);
    const float* xr = x + (size_t)rowc * IN_CH + quad * 8;

    floatx4 acc[4];
#pragma unroll
    for (int ct = 0; ct < 4; ++ct) acc[ct] = (floatx4){0.f, 0.f, 0.f, 0.f};

#pragma unroll
    for (int kc = 0; kc < 4; ++kc) {
        float4 xa = *(const float4*)(xr + kc * 32);
        float4 xb = *(const float4*)(xr + kc * 32 + 4);
        short8 a;
        a[0] = (short)f2bf(xa.x); a[1] = (short)f2bf(xa.y);
        a[2] = (short)f2bf(xa.z); a[3] = (short)f2bf(xa.w);
        a[4] = (short)f2bf(xb.x); a[5] = (short)f2bf(xb.y);
        a[6] = (short)f2bf(xb.z); a[7] = (short)f2bf(xb.w);
#pragma unroll
        for (int ct = 0; ct < 4; ++ct) {
            short8 b = *(const short8*)(Wp + ((((kc * 4 + quad) * 4 + ct) * 16 + m) << 3));
            acc[ct] = __builtin_amdgcn_mfma_f32_16x16x32_bf16(a, b, acc[ct], 0, 0, 0);
        }
    }
    int r0 = blockIdx.x * 64 + wave * 16 + quad * 4;
#pragma unroll
    for (int r = 0; r < 4; ++r) {
        int rr = r0 + r;
        if (rr < n) {
            float di = dinv[rr];
            ushort_t* o = hw1 + (size_t)rr * HID + m;
#pragma unroll
            for (int ct = 0; ct < 4; ++ct) o[ct * 16] = f2bf(acc[ct][r] * di);
        } else if (rr == n) {
            ushort_t* o = hw1 + (size_t)n * HID + m;
#pragma unroll
            for (int ct = 0; ct < 4; ++ct) o[ct * 16] = 0;
        }
    }
}

// ---- agg1: one wave per node; 64-edge register window + shfl broadcast ----
// es holds bare src indices (weights pre-folded into hw1); padding lanes get
// sentinel src=n whose row is all-zero, so over-run iterations add exactly 0.
// All loops wave-uniform (rs/re/nw uniform) -> shfl always sources active lanes.
// 16-edge chunks keep 8 gathers in flight per half (latency-bound regime).
__global__ __launch_bounds__(256) void k_agg1(
    const int* __restrict__ row_start, const uint_t* __restrict__ es,
    const float* __restrict__ dinv, const uint_t* __restrict__ hw1u,
    const float* __restrict__ b1, float* __restrict__ h, int n)
{
    int node = blockIdx.x * 4 + (threadIdx.x >> 6);
    if (node >= n) return;
    int lane = threadIdx.x & 63;
    int half = lane >> 5;
    int l = lane & 31;
    int rs = row_start[node];
    int re = row_start[node + 1];
    float di = dinv[node];

    float2 acc0 = make_float2(0.f, 0.f), acc1 = make_float2(0.f, 0.f);
    if (half == 0) {
        float2 v = unpk(hw1u[node * 32 + l]);  // self term: hw1'[node]
        acc0.x = v.x; acc0.y = v.y;
    }
    for (int base = rs; base < re; base += 64) {
        int nw = re - base; if (nw > 64) nw = 64;
        int idx = base + lane;
        uint_t el = (idx < re) ? es[idx] : (uint_t)n;  // pad -> zero sentinel row
        int j = 0;
        for (; j + 16 <= nw; j += 16) {
            int k0 = j + half;
            int s[8]; uint_t p[8];
#pragma unroll
            for (int u = 0; u < 8; ++u) s[u] = __shfl((int)el, k0 + 2 * u);
#pragma unroll
            for (int u = 0; u < 8; ++u) p[u] = hw1u[s[u] * 32 + l];
#pragma unroll
            for (int u = 0; u < 8; ++u) {
                float2 v = unpk(p[u]);
                if (u & 1) { acc1.x += v.x; acc1.y += v.y; }
                else       { acc0.x += v.x; acc0.y += v.y; }
            }
        }
        if (j + 8 <= nw) {
            int k0 = j + half;
            int s[4]; uint_t p[4];
#pragma unroll
            for (int u = 0; u < 4; ++u) s[u] = __shfl((int)el, k0 + 2 * u);
#pragma unroll
            for (int u = 0; u < 4; ++u) p[u] = hw1u[s[u] * 32 + l];
#pragma unroll
            for (int u = 0; u < 4; ++u) {
                float2 v = unpk(p[u]);
                if (u & 1) { acc1.x += v.x; acc1.y += v.y; }
                else       { acc0.x += v.x; acc0.y += v.y; }
            }
            j += 8;
        }
        int rem = nw - j;
        int iters = (rem + 1) >> 1;   // uniform remainder; k may hit nw -> sentinel adds 0
        for (int it = 0; it < iters; ++it) {
            int k = j + 2 * it + half;
            int s = __shfl((int)el, k);
            float2 v = unpk(hw1u[s * 32 + l]);
            acc1.x += v.x; acc1.y += v.y;
        }
    }
    float ax = (acc0.x + acc1.x), ay = (acc0.y + acc1.y);
    ax += __shfl_xor(ax, 32);
    ay += __shfl_xor(ay, 32);
    if (half == 0) {
        float2 b = ((const float2*)b1)[l];
        float vx = ax * di + b.x, vy = ay * di + b.y;  // dinv_d applied once at the end
        vx = vx > 0.f ? vx : 0.f;
        vy = vy > 0.f ? vy : 0.f;
        ((float2*)h)[node * 32 + l] = make_float2(vx, vy);
    }
}

// ---- GEMM2: hw2 = bf16(dinv * (h @ W2)) (f32 vector ALU, W2 in LDS); row n = zero ----
__global__ __launch_bounds__(256) void k_gemm2(
    const float* __restrict__ h, const float* __restrict__ W2,
    const float* __restrict__ dinv, ushort_t* __restrict__ hw2, int n)
{
    __shared__ float wsm[HID * NC];  // 10 KB
    for (int i = threadIdx.x; i < HID * NC; i += 256) wsm[i] = W2[i];
    __syncthreads();
    int row = blockIdx.x * 256 + threadIdx.x;
    if (row > n) return;
    unsigned int* o = (unsigned int*)(hw2 + (size_t)row * NC);
    if (row == n) {
#pragma unroll
        for (int c2 = 0; c2 < NC / 2; ++c2) o[c2] = 0;  // zero sentinel row
        return;
    }
    const float4* hr = (const float4*)(h + (size_t)row * HID);
    float acc[NC];
#pragma unroll
    for (int c = 0; c < NC; ++c) acc[c] = 0.f;
#pragma unroll 4
    for (int k4 = 0; k4 < HID / 4; ++k4) {
        float4 hv = hr[k4];
        const float* w0 = wsm + (k4 * 4) * NC;
#pragma unroll
        for (int c = 0; c < NC; ++c)
            acc[c] += hv.x * w0[c] + hv.y * w0[c + NC] + hv.z * w0[c + 2 * NC] + hv.w * w0[c + 3 * NC];
    }
    float di = dinv[row];
#pragma unroll
    for (int c2 = 0; c2 < NC / 2; ++c2)
        o[c2] = (unsigned int)f2bf(acc[2 * c2] * di) | ((unsigned int)f2bf(acc[2 * c2 + 1] * di) << 16);
}

// ---- agg2: one wave per node; same structure; lanes 0..19 per half carry channels ----
__global__ __launch_bounds__(256) void k_agg2(
    const int* __restrict__ row_start, const uint_t* __restrict__ es,
    const float* __restrict__ dinv, const uint_t* __restrict__ hw2u,
    const float* __restrict__ b2, float* __restrict__ out, int n)
{
    int node = blockIdx.x * 4 + (threadIdx.x >> 6);
    if (node >= n) return;
    int lane = threadIdx.x & 63;
    int half = lane >> 5;
    int l = lane & 31;
    int li = l < 20 ? l : 0;  // clamp idle lanes to a valid address (coalesces w/ lane 0)
    int rs = row_start[node];
    int re = row_start[node + 1];
    float di = dinv[node];

    float2 acc0 = make_float2(0.f, 0.f), acc1 = make_float2(0.f, 0.f);
    if (half == 0) {
        float2 v = unpk(hw2u[node * 20 + li]);  // self term: hw2'[node]
        acc0.x = v.x; acc0.y = v.y;
    }
    for (int base = rs; base < re; base += 64) {
        int nw = re - base; if (nw > 64) nw = 64;
        int idx = base + lane;
        uint_t el = (idx < re) ? es[idx] : (uint_t)n;  // pad -> zero sentinel row
        int j = 0;
        for (; j + 16 <= nw; j += 16) {
            int k0 = j + half;
            int s[8]; uint_t p[8];
#pragma unroll
            for (int u = 0; u < 8; ++u) s[u] = __shfl((int)el, k0 + 2 * u);
#pragma unroll
            for (int u = 0; u < 8; ++u) p[u] = hw2u[s[u] * 20 + li];
#pragma unroll
            for (int u = 0; u < 8; ++u) {
                float2 v = unpk(p[u]);
                if (u & 1) { acc1.x += v.x; acc1.y += v.y; }
                else       { acc0.x += v.x; acc0.y += v.y; }
            }
        }
        if (j + 8 <= nw) {
            int k0 = j + half;
            int s[4]; uint_t p[4];
#pragma unroll
            for (int u = 0; u < 4; ++u) s[u] = __shfl((int)el, k0 + 2 * u);
#pragma unroll
            for (int u = 0; u < 4; ++u) p[u] = hw2u[s[u] * 20 + li];
#pragma unroll
            for (int u = 0; u < 4; ++u) {
                float2 v = unpk(p[u]);
                if (u & 1) { acc1.x += v.x; acc1.y += v.y; }
                else       { acc0.x += v.x; acc0.y += v.y; }
            }
            j += 8;
        }
        int rem = nw - j;
        int iters = (rem + 1) >> 1;   // uniform remainder (see k_agg1)
        for (int it = 0; it < iters; ++it) {
            int k = j + 2 * it + half;
            int s = __shfl((int)el, k);
            float2 v = unpk(hw2u[s * 20 + li]);
            acc1.x += v.x; acc1.y += v.y;
        }
    }
    float ax = (acc0.x + acc1.x), ay = (acc0.y + acc1.y);
    ax += __shfl_xor(ax, 32);
    ay += __shfl_xor(ay, 32);
    if (half == 0 && l < 20) {
        float2 b = ((const float2*)b2)[l];
        ((float2*)out)[node * 20 + l] = make_float2(ax * di + b.x, ay * di + b.y);
    }
}

extern "C" void kernel_launch(void* const* d_in, const int* in_sizes, int n_in,
                              void* d_out, int out_size, void* d_ws, size_t ws_size,
                              hipStream_t stream) {
    const float* x  = (const float*)d_in[0];   // f32 [N,128]
    const int* edge = (const int*)d_in[1];     // int32 [2,E]
    const float* W1 = (const float*)d_in[2];   // f32 [128,64]
    const float* b1 = (const float*)d_in[3];   // f32 [64]
    const float* W2 = (const float*)d_in[4];   // f32 [64,40]
    const float* b2 = (const float*)d_in[5];   // f32 [40]
    float* out      = (float*)d_out;           // f32 [N,40]

    const int n = in_sizes[0] / IN_CH;   // 100000
    const int e = in_sizes[1] / 2;       // 1600000
    const int* srcs = edge;
    const int* dsts = edge + e;

    // workspace layout: ~61 MB total
    int*      gcur      = (int*)d_ws;                       // 256
    int*      bbase     = gcur + 256;                       // 256
    int*      row_start = bbase + 256;                      // NPAD (needs n+1)
    float*    dinv      = (float*)(row_start + NPAD);       // NPAD
    uint_t*   tmp       = (uint_t*)(dinv + NPAD);           // NBUK*CAP packed 4B
    uint_t*   es        = tmp + (size_t)NBUK * CAP;         // NEDGES src-only 4B
    ushort_t* Wp        = (ushort_t*)(es + NEDGES);         // 8192 bf16
    ushort_t* hw1       = Wp + 8192;                        // (N+1)*64 bf16 (sentinel row n)
    float*    h         = (float*)(hw1 + (size_t)(NNODES + 1) * HID); // N*64 f32
    ushort_t* hw2       = (ushort_t*)(h + (size_t)NNODES * HID);      // (N+1)*40 bf16

    k_ginit<<<1, 256, 0, stream>>>(gcur);
    k_bin0<<<NBIN, 256, 0, stream>>>(srcs, dsts, gcur, tmp, e);
    k_bbase<<<1, 256, 0, stream>>>(gcur, bbase, e);
    k_sort_a<<<NBUK, 256, 0, stream>>>(tmp, gcur, bbase, row_start, dinv, n, e);
    k_sort_b<<<NBUK, 256, 0, stream>>>(tmp, gcur, row_start, es, n);

    k_prepw<<<32, 256, 0, stream>>>(W1, Wp);
    k_gemm1<<<(n + 63) / 64, 256, 0, stream>>>(x, Wp, dinv, hw1, n);
    k_agg1<<<(n + 3) / 4, 256, 0, stream>>>(row_start, es, dinv, (const uint_t*)hw1, b1, h, n);
    k_gemm2<<<(n + 255) / 256, 256, 0, stream>>>(h, W2, dinv, hw2, n);
    k_agg2<<<(n + 3) / 4, 256, 0, stream>>>(row_start, es, dinv, (const uint_t*)hw2, b2, out, n);
}

// Round 2
// 248.647 us; speedup vs baseline: 1.1322x; 1.0895x over previous
//
#include <hip/hip_runtime.h>
#include <hip/hip_bf16.h>

#define NNODES 100000
#define NEDGES 1600000
#define IN_CH 128
#define HID 64
#define NC 40
#define NPAD 100352   // NNODES padded to multiple of 256
#define NBUK 196      // ceil(100000 / 512) dst-buckets of 512 nodes
#define CAP 9216      // per-bucket tmp capacity (mean 8192, sigma ~90 -> 11 sigma)
#define BCHUNK 4096
#define NBIN 391      // ceil(NEDGES / BCHUNK)

typedef unsigned short ushort_t;
typedef unsigned int uint_t;
typedef __attribute__((ext_vector_type(8))) short short8;
typedef __attribute__((ext_vector_type(4))) float floatx4;

__device__ __forceinline__ float bf2f(ushort_t u) {
    union { unsigned int i; float f; } t;
    t.i = ((unsigned int)u) << 16;
    return t.f;
}
__device__ __forceinline__ ushort_t f2bf(float f) {
    union { float ff; unsigned int i; } t;
    t.ff = f;
    unsigned int r = t.i + 0x7fff + ((t.i >> 16) & 1);  // RNE
    return (ushort_t)(r >> 16);
}
// unpack packed bf16x2
__device__ __forceinline__ float2 unpk(uint_t p) {
    union { unsigned int i; float f; } a, b;
    a.i = p << 16;
    b.i = p & 0xffff0000u;
    return make_float2(a.f, b.f);
}

// ---- gcur[b] = b*CAP ----
__global__ void k_ginit(int* __restrict__ gcur) {
    int b = threadIdx.x;
    if (b < NBUK) gcur[b] = b * CAP;
}

// ---- bin edges into bucket-major tmp; entry: src(17b) | local_d(9b)<<17 ----
__global__ __launch_bounds__(256) void k_bin0(
    const int* __restrict__ srcs, const int* __restrict__ dsts,
    int* __restrict__ gcur, uint_t* __restrict__ tmp, int e)
{
    __shared__ uint_t pk[BCHUNK];    // 16 KB
    __shared__ ushort_t bk[BCHUNK];  // 8 KB
    __shared__ int hist[NBUK];
    __shared__ int base[NBUK];
    int t = threadIdx.x;
    int begin = blockIdx.x * BCHUNK;
    int cnt = e - begin; if (cnt > BCHUNK) cnt = BCHUNK;

    for (int i = t; i < NBUK; i += 256) hist[i] = 0;
    __syncthreads();
    for (int j = t; j < cnt; j += 256) {
        int d = dsts[begin + j];
        int s = srcs[begin + j];
        int b = d >> 9;
        pk[j] = (uint_t)s | ((uint_t)(d & 511) << 17);
        bk[j] = (ushort_t)b;
        atomicAdd(&hist[b], 1);
    }
    __syncthreads();
    for (int i = t; i < NBUK; i += 256) {
        base[i] = atomicAdd(&gcur[i], hist[i]);  // reserve segment in bucket i
        hist[i] = 0;                             // reuse as local rank cursor
    }
    __syncthreads();
    for (int j = t; j < cnt; j += 256) {
        int b = bk[j];
        int r = atomicAdd(&hist[b], 1);
        int pos = base[b] + r;
        if (pos < (b + 1) * CAP) tmp[pos] = pk[j];  // burst writes; guard vs overflow
    }
}

// ---- exclusive scan of bucket totals -> bbase[0..NBUK], single block ----
__global__ __launch_bounds__(256) void k_bbase(const int* __restrict__ gcur,
                                               int* __restrict__ bbase, int e) {
    __shared__ int s[256];
    int t = threadIdx.x;
    int c = (t < NBUK) ? (gcur[t] - t * CAP) : 0;
    s[t] = c;
    __syncthreads();
    for (int off = 1; off < 256; off <<= 1) {
        int v = (t >= off) ? s[t - off] : 0;
        __syncthreads();
        s[t] += v;
        __syncthreads();
    }
    if (t < NBUK) bbase[t] = s[t] - c;
    if (t == 0) bbase[NBUK] = e;
}

// ---- per-bucket: count per node (LDS), scan 512, write row_start + dinv ----
__global__ __launch_bounds__(256) void k_sort_a(
    const uint_t* __restrict__ tmp, const int* __restrict__ gcur,
    const int* __restrict__ bbase, int* __restrict__ row_start,
    float* __restrict__ dinv, int n, int e)
{
    __shared__ int cnt[512];
    __shared__ int sc[512];
    int t = threadIdx.x;
    int b = blockIdx.x;
    int d0 = b << 9;
    int total = gcur[b] - b * CAP;
    cnt[t] = 0; cnt[t + 256] = 0;
    __syncthreads();
    const uint_t* seg = tmp + b * CAP;
    for (int j = t; j < total; j += 256)
        atomicAdd(&cnt[seg[j] >> 17], 1);
    __syncthreads();
    sc[t] = cnt[t]; sc[t + 256] = cnt[t + 256];
    __syncthreads();
    for (int off = 1; off < 512; off <<= 1) {
        int v0 = (t >= off) ? sc[t - off] : 0;
        int i1 = t + 256;
        int v1 = (i1 >= off) ? sc[i1 - off] : 0;
        __syncthreads();
        sc[t] += v0; sc[i1] += v1;
        __syncthreads();
    }
    int gb = bbase[b];
#pragma unroll
    for (int q = 0; q < 2; ++q) {
        int i = t + q * 256;
        int node = d0 + i;
        if (node < n) {
            row_start[node] = gb + sc[i] - cnt[i];
            dinv[node] = rsqrtf((float)cnt[i] + 1.0f);
        }
    }
    if (b == NBUK - 1 && t == 0) row_start[n] = e;
}

// ---- per-bucket: scatter src indices to final CSR order (dinv folded into hw rows) ----
__global__ __launch_bounds__(256) void k_sort_b(
    const uint_t* __restrict__ tmp, const int* __restrict__ gcur,
    const int* __restrict__ row_start, uint_t* __restrict__ es, int n)
{
    __shared__ int cur[512];
    int t = threadIdx.x;
    int b = blockIdx.x;
    int d0 = b << 9;
    int total = gcur[b] - b * CAP;
#pragma unroll
    for (int q = 0; q < 2; ++q) {
        int i = t + q * 256;
        int node = d0 + i;
        cur[i] = (node < n) ? row_start[node] : 0;
    }
    __syncthreads();
    const uint_t* seg = tmp + b * CAP;
    for (int j = t; j < total; j += 256) {
        uint_t p = seg[j];                 // coalesced
        int ld = (int)(p >> 17);
        int pos = atomicAdd(&cur[ld], 1);
        es[pos] = p & 0x1FFFFu;            // src only; weight folded into hw rows
    }
}

// ---- pre-swizzle W1 (f32) into bf16 B-fragment order ----
__global__ void k_prepw(const float* __restrict__ W1, ushort_t* __restrict__ Wp) {
    int i = blockIdx.x * 256 + threadIdx.x;
    if (i >= IN_CH * HID) return;
    int j = i & 7;
    int m = (i >> 3) & 15;
    int ct = (i >> 7) & 3;
    int quad = (i >> 9) & 3;
    int kc = i >> 11;
    int k = kc * 32 + quad * 8 + j;
    int c = ct * 16 + m;
    Wp[i] = f2bf(W1[k * HID + c]);
}

// ---- GEMM1: hw1 = bf16(dinv * (x @ W1)) via MFMA; row n = zero sentinel ----
__global__ __launch_bounds__(256) void k_gemm1(
    const float* __restrict__ x, const ushort_t* __restrict__ Wp,
    const float* __restrict__ dinv, ushort_t* __restrict__ hw1, int n)
{
    int wave = threadIdx.x >> 6;
    int lane = threadIdx.x & 63;
    int m = lane & 15;
    int quad = lane >> 4;
    int row = blockIdx.x * 64 + wave * 16 + m;
    int rowc = row < n ? row : (n - 1);
    const float* xr = x + (size_t)rowc * IN_CH + quad * 8;

    floatx4 acc[4];
#pragma unroll
    for (int ct = 0; ct < 4; ++ct) acc[ct] = (floatx4){0.f, 0.f, 0.f, 0.f};

#pragma unroll
    for (int kc = 0; kc < 4; ++kc) {
        float4 xa = *(const float4*)(xr + kc * 32);
        float4 xb = *(const float4*)(xr + kc * 32 + 4);
        short8 a;
        a[0] = (short)f2bf(xa.x); a[1] = (short)f2bf(xa.y);
        a[2] = (short)f2bf(xa.z); a[3] = (short)f2bf(xa.w);
        a[4] = (short)f2bf(xb.x); a[5] = (short)f2bf(xb.y);
        a[6] = (short)f2bf(xb.z); a[7] = (short)f2bf(xb.w);
#pragma unroll
        for (int ct = 0; ct < 4; ++ct) {
            short8 b = *(const short8*)(Wp + ((((kc * 4 + quad) * 4 + ct) * 16 + m) << 3));
            acc[ct] = __builtin_amdgcn_mfma_f32_16x16x32_bf16(a, b, acc[ct], 0, 0, 0);
        }
    }
    int r0 = blockIdx.x * 64 + wave * 16 + quad * 4;
#pragma unroll
    for (int r = 0; r < 4; ++r) {
        int rr = r0 + r;
        if (rr < n) {
            float di = dinv[rr];
            ushort_t* o = hw1 + (size_t)rr * HID + m;
#pragma unroll
            for (int ct = 0; ct < 4; ++ct) o[ct * 16] = f2bf(acc[ct][r] * di);
        } else if (rr == n) {
            ushort_t* o = hw1 + (size_t)n * HID + m;
#pragma unroll
            for (int ct = 0; ct < 4; ++ct) o[ct * 16] = 0;
        }
    }
}

// ---- agg1: one QUARTER-wave (16 lanes) per node ----
// Row = 64ch bf16 = 16 lanes x dwordx2; one gather instruction serves 4 edges
// (one per quarter). 4 independent node-chains per wave hide gather latency.
// es holds bare src indices; sentinel row n is all-zero, so padded window
// slots (el=n) contribute exactly 0 -> no remainder logic. All shfl sources
// are within the own quarter, which is uniformly active (rs/re uniform per
// quarter) -> never sources exec-masked lanes.
__global__ __launch_bounds__(256) void k_agg1(
    const int* __restrict__ row_start, const uint_t* __restrict__ es,
    const float* __restrict__ dinv, const uint_t* __restrict__ hw1u,
    const float* __restrict__ b1, float* __restrict__ h, int n)
{
    int lane = threadIdx.x & 63;
    int qbase = lane & 48;              // quarter's first lane in the wave
    int ll = lane & 15;
    int node = blockIdx.x * 16 + (threadIdx.x >> 4);   // 16 quarters / block
    bool valid = node < n;
    int rs = valid ? row_start[node] : 0;
    int re = valid ? row_start[node + 1] : 0;
    float di = valid ? dinv[node] : 0.f;
    int selfrow = valid ? node : n;

    float a0, a1, a2, a3;
    {
        uint2 p = *(const uint2*)(hw1u + (size_t)selfrow * 32 + ll * 2);
        float2 v0 = unpk(p.x), v1 = unpk(p.y);
        a0 = v0.x; a1 = v0.y; a2 = v1.x; a3 = v1.y;
    }
    for (int base = rs; base < re; base += 16) {
        int idx = base + ll;
        int el = (idx < re) ? (int)es[idx] : n;        // pad -> zero sentinel
        int nw = re - base;                            // uniform per quarter
        uint2 pA[8], pB[8];
#pragma unroll
        for (int b = 0; b < 8; ++b) {
            int s = __shfl(el, qbase + b);
            pA[b] = *(const uint2*)(hw1u + (size_t)s * 32 + ll * 2);
        }
        bool more = nw > 8;
        if (more) {
#pragma unroll
            for (int b = 0; b < 8; ++b) {
                int s = __shfl(el, qbase + 8 + b);
                pB[b] = *(const uint2*)(hw1u + (size_t)s * 32 + ll * 2);
            }
        }
#pragma unroll
        for (int b = 0; b < 8; ++b) {
            float2 v0 = unpk(pA[b].x), v1 = unpk(pA[b].y);
            a0 += v0.x; a1 += v0.y; a2 += v1.x; a3 += v1.y;
        }
        if (more) {
#pragma unroll
            for (int b = 0; b < 8; ++b) {
                float2 v0 = unpk(pB[b].x), v1 = unpk(pB[b].y);
                a0 += v0.x; a1 += v0.y; a2 += v1.x; a3 += v1.y;
            }
        }
    }
    if (valid) {
        float4 bb = ((const float4*)b1)[ll];   // channels 4*ll .. 4*ll+3
        float4 o;
        o.x = fmaxf(a0 * di + bb.x, 0.f);
        o.y = fmaxf(a1 * di + bb.y, 0.f);
        o.z = fmaxf(a2 * di + bb.z, 0.f);
        o.w = fmaxf(a3 * di + bb.w, 0.f);
        ((float4*)(h + (size_t)node * 64))[ll] = o;
    }
}

// ---- GEMM2: hw2 = bf16(dinv * (h @ W2)) (f32 vector ALU, W2 in LDS); row n = zero ----
__global__ __launch_bounds__(256) void k_gemm2(
    const float* __restrict__ h, const float* __restrict__ W2,
    const float* __restrict__ dinv, ushort_t* __restrict__ hw2, int n)
{
    __shared__ float wsm[HID * NC];  // 10 KB
    for (int i = threadIdx.x; i < HID * NC; i += 256) wsm[i] = W2[i];
    __syncthreads();
    int row = blockIdx.x * 256 + threadIdx.x;
    if (row > n) return;
    unsigned int* o = (unsigned int*)(hw2 + (size_t)row * NC);
    if (row == n) {
#pragma unroll
        for (int c2 = 0; c2 < NC / 2; ++c2) o[c2] = 0;  // zero sentinel row
        return;
    }
    const float4* hr = (const float4*)(h + (size_t)row * HID);
    float acc[NC];
#pragma unroll
    for (int c = 0; c < NC; ++c) acc[c] = 0.f;
#pragma unroll 4
    for (int k4 = 0; k4 < HID / 4; ++k4) {
        float4 hv = hr[k4];
        const float* w0 = wsm + (k4 * 4) * NC;
#pragma unroll
        for (int c = 0; c < NC; ++c)
            acc[c] += hv.x * w0[c] + hv.y * w0[c + NC] + hv.z * w0[c + 2 * NC] + hv.w * w0[c + 3 * NC];
    }
    float di = dinv[row];
#pragma unroll
    for (int c2 = 0; c2 < NC / 2; ++c2)
        o[c2] = (unsigned int)f2bf(acc[2 * c2] * di) | ((unsigned int)f2bf(acc[2 * c2 + 1] * di) << 16);
}

// ---- agg2: one QUARTER-wave per node; row = 20 uints on lanes 0..9 (dwordx2) ----
// Lanes 10..15 clamp to a safe in-row address (dup of lane 0); their acc is
// garbage but never stored. They still carry window edges for the shfl.
__global__ __launch_bounds__(256) void k_agg2(
    const int* __restrict__ row_start, const uint_t* __restrict__ es,
    const float* __restrict__ dinv, const uint_t* __restrict__ hw2u,
    const float* __restrict__ b2, float* __restrict__ out, int n)
{
    int lane = threadIdx.x & 63;
    int qbase = lane & 48;
    int ll = lane & 15;
    int lc = (ll < 10) ? ll : 0;        // clamped data-lane index
    int node = blockIdx.x * 16 + (threadIdx.x >> 4);
    bool valid = node < n;
    int rs = valid ? row_start[node] : 0;
    int re = valid ? row_start[node + 1] : 0;
    float di = valid ? dinv[node] : 0.f;
    int selfrow = valid ? node : n;

    float a0, a1, a2, a3;
    {
        uint2 p = *(const uint2*)(hw2u + (size_t)selfrow * 20 + lc * 2);
        float2 v0 = unpk(p.x), v1 = unpk(p.y);
        a0 = v0.x; a1 = v0.y; a2 = v1.x; a3 = v1.y;
    }
    for (int base = rs; base < re; base += 16) {
        int idx = base + ll;
        int el = (idx < re) ? (int)es[idx] : n;        // pad -> zero sentinel
        int nw = re - base;                            // uniform per quarter
        uint2 pA[8], pB[8];
#pragma unroll
        for (int b = 0; b < 8; ++b) {
            int s = __shfl(el, qbase + b);
            pA[b] = *(const uint2*)(hw2u + (size_t)s * 20 + lc * 2);
        }
        bool more = nw > 8;
        if (more) {
#pragma unroll
            for (int b = 0; b < 8; ++b) {
                int s = __shfl(el, qbase + 8 + b);
                pB[b] = *(const uint2*)(hw2u + (size_t)s * 20 + lc * 2);
            }
        }
#pragma unroll
        for (int b = 0; b < 8; ++b) {
            float2 v0 = unpk(pA[b].x), v1 = unpk(pA[b].y);
            a0 += v0.x; a1 += v0.y; a2 += v1.x; a3 += v1.y;
        }
        if (more) {
#pragma unroll
            for (int b = 0; b < 8; ++b) {
                float2 v0 = unpk(pB[b].x), v1 = unpk(pB[b].y);
                a0 += v0.x; a1 += v0.y; a2 += v1.x; a3 += v1.y;
            }
        }
    }
    if (valid && ll < 10) {
        float4 bb = ((const float4*)b2)[ll];   // channels 4*ll .. 4*ll+3
        float4 o;
        o.x = a0 * di + bb.x;
        o.y = a1 * di + bb.y;
        o.z = a2 * di + bb.z;
        o.w = a3 * di + bb.w;
        ((float4*)(out + (size_t)node * 40))[ll] = o;
    }
}

extern "C" void kernel_launch(void* const* d_in, const int* in_sizes, int n_in,
                              void* d_out, int out_size, void* d_ws, size_t ws_size,
                              hipStream_t stream) {
    const float* x  = (const float*)d_in[0];   // f32 [N,128]
    const int* edge = (const int*)d_in[1];     // int32 [2,E]
    const float* W1 = (const float*)d_in[2];   // f32 [128,64]
    const float* b1 = (const float*)d_in[3];   // f32 [64]
    const float* W2 = (const float*)d_in[4];   // f32 [64,40]
    const float* b2 = (const float*)d_in[5];   // f32 [40]
    float* out      = (float*)d_out;           // f32 [N,40]

    const int n = in_sizes[0] / IN_CH;   // 100000
    const int e = in_sizes[1] / 2;       // 1600000
    const int* srcs = edge;
    const int* dsts = edge + e;

    // workspace layout: ~61 MB total (all segments 16B-aligned)
    int*      gcur      = (int*)d_ws;                       // 256
    int*      bbase     = gcur + 256;                       // 256
    int*      row_start = bbase + 256;                      // NPAD (needs n+1)
    float*    dinv      = (float*)(row_start + NPAD);       // NPAD
    uint_t*   tmp       = (uint_t*)(dinv + NPAD);           // NBUK*CAP packed 4B
    uint_t*   es        = tmp + (size_t)NBUK * CAP;         // NEDGES src-only 4B
    ushort_t* Wp        = (ushort_t*)(es + NEDGES);         // 8192 bf16
    ushort_t* hw1       = Wp + 8192;                        // (N+1)*64 bf16 (sentinel row n)
    float*    h         = (float*)(hw1 + (size_t)(NNODES + 1) * HID); // N*64 f32
    ushort_t* hw2       = (ushort_t*)(h + (size_t)NNODES * HID);      // (N+1)*40 bf16

    k_ginit<<<1, 256, 0, stream>>>(gcur);
    k_bin0<<<NBIN, 256, 0, stream>>>(srcs, dsts, gcur, tmp, e);
    k_bbase<<<1, 256, 0, stream>>>(gcur, bbase, e);
    k_sort_a<<<NBUK, 256, 0, stream>>>(tmp, gcur, bbase, row_start, dinv, n, e);
    k_sort_b<<<NBUK, 256, 0, stream>>>(tmp, gcur, row_start, es, n);

    k_prepw<<<32, 256, 0, stream>>>(W1, Wp);
    k_gemm1<<<(n + 63) / 64, 256, 0, stream>>>(x, Wp, dinv, hw1, n);
    k_agg1<<<(n + 15) / 16, 256, 0, stream>>>(row_start, es, dinv, (const uint_t*)hw1, b1, h, n);
    k_gemm2<<<(n + 255) / 256, 256, 0, stream>>>(h, W2, dinv, hw2, n);
    k_agg2<<<(n + 15) / 16, 256, 0, stream>>>(row_start, es, dinv, (const uint_t*)hw2, b2, out, n);
}

// Round 3
// 228.080 us; speedup vs baseline: 1.2343x; 1.0902x over previous
//
#include <hip/hip_runtime.h>
#include <hip/hip_bf16.h>

#define NNODES 100000
#define NEDGES 1600000
#define IN_CH 128
#define HID 64
#define NC 40
#define NPAD 100352   // NNODES padded to multiple of 256
#define NBUK 196      // ceil(100000 / 512) dst-buckets of 512 nodes
#define CAP 9216      // per-bucket tmp capacity (mean 8192, sigma ~90 -> 11 sigma)
#define BCHUNK 4096
#define NBIN 391      // ceil(NEDGES / BCHUNK)
#define HW2S 64       // hw2 row stride in ushorts (128 B line-aligned; 40 used)

typedef unsigned short ushort_t;
typedef unsigned int uint_t;
typedef __attribute__((ext_vector_type(8))) short short8;
typedef __attribute__((ext_vector_type(4))) float floatx4;

__device__ __forceinline__ float bf2f(ushort_t u) {
    union { unsigned int i; float f; } t;
    t.i = ((unsigned int)u) << 16;
    return t.f;
}
__device__ __forceinline__ ushort_t f2bf(float f) {
    union { float ff; unsigned int i; } t;
    t.ff = f;
    unsigned int r = t.i + 0x7fff + ((t.i >> 16) & 1);  // RNE
    return (ushort_t)(r >> 16);
}
// unpack packed bf16x2
__device__ __forceinline__ float2 unpk(uint_t p) {
    union { unsigned int i; float f; } a, b;
    a.i = p << 16;
    b.i = p & 0xffff0000u;
    return make_float2(a.f, b.f);
}

// ---- init: Wp swizzle (blocks 0..31) + gcur init + hw2 zero-sentinel (block 32) ----
__global__ __launch_bounds__(256) void k_init(
    const float* __restrict__ W1, ushort_t* __restrict__ Wp,
    int* __restrict__ gcur, ushort_t* __restrict__ hw2, int n)
{
    int b = blockIdx.x, t = threadIdx.x;
    if (b < 32) {
        int i = b * 256 + t;           // < 8192
        int j = i & 7;
        int m = (i >> 3) & 15;
        int ct = (i >> 7) & 3;
        int quad = (i >> 9) & 3;
        int kc = i >> 11;
        int k = kc * 32 + quad * 8 + j;
        int c = ct * 16 + m;
        Wp[i] = f2bf(W1[k * HID + c]);
    } else {
        if (t < NBUK) gcur[t] = t * CAP;
        if (t >= 224 && t < 224 + NC) hw2[(size_t)n * HW2S + (t - 224)] = 0;
    }
}

// ---- bin edges into bucket-major tmp; entry: src(17b) | local_d(9b)<<17 ----
__global__ __launch_bounds__(256) void k_bin0(
    const int* __restrict__ srcs, const int* __restrict__ dsts,
    int* __restrict__ gcur, uint_t* __restrict__ tmp, int e)
{
    __shared__ uint_t pk[BCHUNK];    // 16 KB
    __shared__ ushort_t bk[BCHUNK];  // 8 KB
    __shared__ int hist[NBUK];
    __shared__ int base[NBUK];
    int t = threadIdx.x;
    int begin = blockIdx.x * BCHUNK;
    int cnt = e - begin; if (cnt > BCHUNK) cnt = BCHUNK;

    for (int i = t; i < NBUK; i += 256) hist[i] = 0;
    __syncthreads();
    for (int j = t; j < cnt; j += 256) {
        int d = dsts[begin + j];
        int s = srcs[begin + j];
        int b = d >> 9;
        pk[j] = (uint_t)s | ((uint_t)(d & 511) << 17);
        bk[j] = (ushort_t)b;
        atomicAdd(&hist[b], 1);
    }
    __syncthreads();
    for (int i = t; i < NBUK; i += 256) {
        base[i] = atomicAdd(&gcur[i], hist[i]);  // reserve segment in bucket i
        hist[i] = 0;                             // reuse as local rank cursor
    }
    __syncthreads();
    for (int j = t; j < cnt; j += 256) {
        int b = bk[j];
        int r = atomicAdd(&hist[b], 1);
        int pos = base[b] + r;
        if (pos < (b + 1) * CAP) tmp[pos] = pk[j];  // burst writes; guard vs overflow
    }
}

// ---- merged sort: per-bucket count + scan + row_start/dinv + scatter to es ----
// Each block computes its own global base gb = sum of counts of buckets < b
// (196 reads of gcur, tree-reduced in LDS) -> k_bbase kernel eliminated.
__global__ __launch_bounds__(256) void k_sort(
    const uint_t* __restrict__ tmp, const int* __restrict__ gcur,
    int* __restrict__ row_start, float* __restrict__ dinv,
    uint_t* __restrict__ es, int n, int e)
{
    __shared__ int cnt[512];
    __shared__ int sc[512];
    __shared__ int red[256];
    int t = threadIdx.x;
    int b = blockIdx.x;
    int d0 = b << 9;
    int total = gcur[b] - b * CAP;
    if (total > CAP) total = CAP;
    // gb = exclusive prefix over bucket totals
    int part = 0;
    for (int i = t; i < b; i += 256) part += gcur[i] - i * CAP;
    red[t] = part;
    cnt[t] = 0; cnt[t + 256] = 0;
    __syncthreads();
    for (int off = 128; off > 0; off >>= 1) {
        if (t < off) red[t] += red[t + off];
        __syncthreads();
    }
    int gb = red[0];
    // count per node
    const uint_t* seg = tmp + b * CAP;
    for (int j = t; j < total; j += 256)
        atomicAdd(&cnt[seg[j] >> 17], 1);
    __syncthreads();
    sc[t] = cnt[t]; sc[t + 256] = cnt[t + 256];
    __syncthreads();
    for (int off = 1; off < 512; off <<= 1) {
        int v0 = (t >= off) ? sc[t - off] : 0;
        int i1 = t + 256;
        int v1 = (i1 >= off) ? sc[i1 - off] : 0;
        __syncthreads();
        sc[t] += v0; sc[i1] += v1;
        __syncthreads();
    }
#pragma unroll
    for (int q = 0; q < 2; ++q) {
        int i = t + q * 256;
        int node = d0 + i;
        int start = gb + sc[i] - cnt[i];
        if (node < n) {
            row_start[node] = start;
            dinv[node] = rsqrtf((float)cnt[i] + 1.0f);
        }
        cnt[i] = start;   // reuse cnt as scatter cursor (own-thread overwrite)
    }
    __syncthreads();
    // scatter to final CSR order
    for (int j = t; j < total; j += 256) {
        uint_t p = seg[j];
        int ld = (int)(p >> 17);
        int pos = atomicAdd(&cnt[ld], 1);
        es[pos] = p & 0x1FFFFu;
    }
    if (b == NBUK - 1 && t == 0) row_start[n] = e;
}

// ---- GEMM1: hw1 = bf16(dinv * (x @ W1)) via MFMA; row n = zero sentinel ----
__global__ __launch_bounds__(256) void k_gemm1(
    const float* __restrict__ x, const ushort_t* __restrict__ Wp,
    const float* __restrict__ dinv, ushort_t* __restrict__ hw1, int n)
{
    int wave = threadIdx.x >> 6;
    int lane = threadIdx.x & 63;
    int m = lane & 15;
    int quad = lane >> 4;
    int row = blockIdx.x * 64 + wave * 16 + m;
    int rowc = row < n ? row : (n - 1);
    const float* xr = x + (size_t)rowc * IN_CH + quad * 8;

    floatx4 acc[4];
#pragma unroll
    for (int ct = 0; ct < 4; ++ct) acc[ct] = (floatx4){0.f, 0.f, 0.f, 0.f};

#pragma unroll
    for (int kc = 0; kc < 4; ++kc) {
        float4 xa = *(const float4*)(xr + kc * 32);
        float4 xb = *(const float4*)(xr + kc * 32 + 4);
        short8 a;
        a[0] = (short)f2bf(xa.x); a[1] = (short)f2bf(xa.y);
        a[2] = (short)f2bf(xa.z); a[3] = (short)f2bf(xa.w);
        a[4] = (short)f2bf(xb.x); a[5] = (short)f2bf(xb.y);
        a[6] = (short)f2bf(xb.z); a[7] = (short)f2bf(xb.w);
#pragma unroll
        for (int ct = 0; ct < 4; ++ct) {
            short8 b = *(const short8*)(Wp + ((((kc * 4 + quad) * 4 + ct) * 16 + m) << 3));
            acc[ct] = __builtin_amdgcn_mfma_f32_16x16x32_bf16(a, b, acc[ct], 0, 0, 0);
        }
    }
    int r0 = blockIdx.x * 64 + wave * 16 + quad * 4;
#pragma unroll
    for (int r = 0; r < 4; ++r) {
        int rr = r0 + r;
        if (rr < n) {
            float di = dinv[rr];
            ushort_t* o = hw1 + (size_t)rr * HID + m;
#pragma unroll
            for (int ct = 0; ct < 4; ++ct) o[ct * 16] = f2bf(acc[ct][r] * di);
        } else if (rr == n) {
            ushort_t* o = hw1 + (size_t)n * HID + m;
#pragma unroll
            for (int ct = 0; ct < 4; ++ct) o[ct * 16] = 0;
        }
    }
}

// ---- agg1 + fused GEMM2: one quarter-wave per node ----
// Gather phase identical to round 2. Epilogue: h-row (relu'd, f32) -> LDS
// (stride 68 floats: conflict-free across the wave's 4 quarters), then each
// quarter computes its node's 40-ch h@W2 dot against LDS-resident W2 and
// emits the bf16 hw2 row directly (128 B stride). h never touches global.
// Producer and consumer lanes of the h tile are the same wave -> no barrier.
__global__ __launch_bounds__(256) void k_agg1(
    const int* __restrict__ row_start, const uint_t* __restrict__ es,
    const float* __restrict__ dinv, const uint_t* __restrict__ hw1u,
    const float* __restrict__ b1, const float* __restrict__ W2,
    ushort_t* __restrict__ hw2, int n)
{
    __shared__ float wsm[HID * NC];   // 10 KB, W2 row-major [64][40]
    __shared__ float hsm[16][68];     // 16 nodes x 64ch, pad->bank-clean
    for (int i = threadIdx.x; i < HID * NC; i += 256) wsm[i] = W2[i];
    __syncthreads();

    int lane = threadIdx.x & 63;
    int qbase = lane & 48;              // quarter's first lane in the wave
    int ll = lane & 15;
    int q16 = threadIdx.x >> 4;         // node slot within block (0..15)
    int node = blockIdx.x * 16 + q16;
    bool valid = node < n;
    int rs = valid ? row_start[node] : 0;
    int re = valid ? row_start[node + 1] : 0;
    float di = valid ? dinv[node] : 0.f;
    int selfrow = valid ? node : n;

    float a0, a1, a2, a3;
    {
        uint2 p = *(const uint2*)(hw1u + (size_t)selfrow * 32 + ll * 2);
        float2 v0 = unpk(p.x), v1 = unpk(p.y);
        a0 = v0.x; a1 = v0.y; a2 = v1.x; a3 = v1.y;
    }
    for (int base = rs; base < re; base += 16) {
        int idx = base + ll;
        int el = (idx < re) ? (int)es[idx] : n;        // pad -> zero sentinel
        int nw = re - base;                            // uniform per quarter
        uint2 pA[8], pB[8];
#pragma unroll
        for (int b = 0; b < 8; ++b) {
            int s = __shfl(el, qbase + b);
            pA[b] = *(const uint2*)(hw1u + (size_t)s * 32 + ll * 2);
        }
        bool more = nw > 8;
        if (more) {
#pragma unroll
            for (int b = 0; b < 8; ++b) {
                int s = __shfl(el, qbase + 8 + b);
                pB[b] = *(const uint2*)(hw1u + (size_t)s * 32 + ll * 2);
            }
        }
#pragma unroll
        for (int b = 0; b < 8; ++b) {
            float2 v0 = unpk(pA[b].x), v1 = unpk(pA[b].y);
            a0 += v0.x; a1 += v0.y; a2 += v1.x; a3 += v1.y;
        }
        if (more) {
#pragma unroll
            for (int b = 0; b < 8; ++b) {
                float2 v0 = unpk(pB[b].x), v1 = unpk(pB[b].y);
                a0 += v0.x; a1 += v0.y; a2 += v1.x; a3 += v1.y;
            }
        }
    }
    // h = relu(agg*di + b1) -> LDS tile (garbage for invalid nodes: never stored)
    float4 hv;
    {
        float4 bb = ((const float4*)b1)[ll];   // channels 4*ll .. 4*ll+3
        hv.x = fmaxf(a0 * di + bb.x, 0.f);
        hv.y = fmaxf(a1 * di + bb.y, 0.f);
        hv.z = fmaxf(a2 * di + bb.z, 0.f);
        hv.w = fmaxf(a3 * di + bb.w, 0.f);
    }
    *(float4*)&hsm[q16][ll * 4] = hv;
    // fused GEMM2: lanes 0..9 each produce 4 output channels
    int lw = (ll < 10) ? ll : 0;
    const float4* w4 = (const float4*)wsm;     // [64][10] float4
    float4 acc = make_float4(0.f, 0.f, 0.f, 0.f);
#pragma unroll 4
    for (int k4 = 0; k4 < 16; ++k4) {
        float4 hk = *(const float4*)&hsm[q16][k4 * 4];
        float4 w0 = w4[(k4 * 4 + 0) * 10 + lw];
        float4 w1 = w4[(k4 * 4 + 1) * 10 + lw];
        float4 w2 = w4[(k4 * 4 + 2) * 10 + lw];
        float4 w3 = w4[(k4 * 4 + 3) * 10 + lw];
        acc.x += hk.x * w0.x + hk.y * w1.x + hk.z * w2.x + hk.w * w3.x;
        acc.y += hk.x * w0.y + hk.y * w1.y + hk.z * w2.y + hk.w * w3.y;
        acc.z += hk.x * w0.z + hk.y * w1.z + hk.z * w2.z + hk.w * w3.z;
        acc.w += hk.x * w0.w + hk.y * w1.w + hk.z * w2.w + hk.w * w3.w;
    }
    if (valid && ll < 10) {
        uint2 st;
        st.x = (uint_t)f2bf(acc.x * di) | ((uint_t)f2bf(acc.y * di) << 16);
        st.y = (uint_t)f2bf(acc.z * di) | ((uint_t)f2bf(acc.w * di) << 16);
        *(uint2*)(hw2 + (size_t)node * HW2S + ll * 4) = st;
    }
}

// ---- agg2: one quarter-wave per node; hw2 rows at 128 B stride (1 line/gather) ----
__global__ __launch_bounds__(256) void k_agg2(
    const int* __restrict__ row_start, const uint_t* __restrict__ es,
    const float* __restrict__ dinv, const uint_t* __restrict__ hw2u,
    const float* __restrict__ b2, float* __restrict__ out, int n)
{
    int lane = threadIdx.x & 63;
    int qbase = lane & 48;
    int ll = lane & 15;
    int lc = (ll < 10) ? ll : 0;        // clamped data-lane index
    int node = blockIdx.x * 16 + (threadIdx.x >> 4);
    bool valid = node < n;
    int rs = valid ? row_start[node] : 0;
    int re = valid ? row_start[node + 1] : 0;
    float di = valid ? dinv[node] : 0.f;
    int selfrow = valid ? node : n;

    float a0, a1, a2, a3;
    {
        uint2 p = *(const uint2*)(hw2u + (size_t)selfrow * (HW2S / 2) + lc * 2);
        float2 v0 = unpk(p.x), v1 = unpk(p.y);
        a0 = v0.x; a1 = v0.y; a2 = v1.x; a3 = v1.y;
    }
    for (int base = rs; base < re; base += 16) {
        int idx = base + ll;
        int el = (idx < re) ? (int)es[idx] : n;        // pad -> zero sentinel
        int nw = re - base;                            // uniform per quarter
        uint2 pA[8], pB[8];
#pragma unroll
        for (int b = 0; b < 8; ++b) {
            int s = __shfl(el, qbase + b);
            pA[b] = *(const uint2*)(hw2u + (size_t)s * (HW2S / 2) + lc * 2);
        }
        bool more = nw > 8;
        if (more) {
#pragma unroll
            for (int b = 0; b < 8; ++b) {
                int s = __shfl(el, qbase + 8 + b);
                pB[b] = *(const uint2*)(hw2u + (size_t)s * (HW2S / 2) + lc * 2);
            }
        }
#pragma unroll
        for (int b = 0; b < 8; ++b) {
            float2 v0 = unpk(pA[b].x), v1 = unpk(pA[b].y);
            a0 += v0.x; a1 += v0.y; a2 += v1.x; a3 += v1.y;
        }
        if (more) {
#pragma unroll
            for (int b = 0; b < 8; ++b) {
                float2 v0 = unpk(pB[b].x), v1 = unpk(pB[b].y);
                a0 += v0.x; a1 += v0.y; a2 += v1.x; a3 += v1.y;
            }
        }
    }
    if (valid && ll < 10) {
        float4 bb = ((const float4*)b2)[ll];   // channels 4*ll .. 4*ll+3
        float4 o;
        o.x = a0 * di + bb.x;
        o.y = a1 * di + bb.y;
        o.z = a2 * di + bb.z;
        o.w = a3 * di + bb.w;
        ((float4*)(out + (size_t)node * 40))[ll] = o;
    }
}

extern "C" void kernel_launch(void* const* d_in, const int* in_sizes, int n_in,
                              void* d_out, int out_size, void* d_ws, size_t ws_size,
                              hipStream_t stream) {
    const float* x  = (const float*)d_in[0];   // f32 [N,128]
    const int* edge = (const int*)d_in[1];     // int32 [2,E]
    const float* W1 = (const float*)d_in[2];   // f32 [128,64]
    const float* b1 = (const float*)d_in[3];   // f32 [64]
    const float* W2 = (const float*)d_in[4];   // f32 [64,40]
    const float* b2 = (const float*)d_in[5];   // f32 [40]
    float* out      = (float*)d_out;           // f32 [N,40]

    const int n = in_sizes[0] / IN_CH;   // 100000
    const int e = in_sizes[1] / 2;       // 1600000
    const int* srcs = edge;
    const int* dsts = edge + e;

    // workspace layout (all segments 16B-aligned)
    int*      gcur      = (int*)d_ws;                       // 256
    int*      row_start = gcur + 256;                       // NPAD (needs n+1)
    float*    dinv      = (float*)(row_start + NPAD);       // NPAD
    uint_t*   tmp       = (uint_t*)(dinv + NPAD);           // NBUK*CAP packed 4B
    uint_t*   es        = tmp + (size_t)NBUK * CAP;         // NEDGES src-only 4B
    ushort_t* Wp        = (ushort_t*)(es + NEDGES);         // 8192 bf16
    ushort_t* hw1       = Wp + 8192;                        // (N+1)*64 bf16 (sentinel row n)
    ushort_t* hw2       = hw1 + (size_t)(NNODES + 1) * HID; // (N+1)*HW2S bf16 (40 used)

    k_init<<<33, 256, 0, stream>>>(W1, Wp, gcur, hw2, n);
    k_bin0<<<NBIN, 256, 0, stream>>>(srcs, dsts, gcur, tmp, e);
    k_sort<<<NBUK, 256, 0, stream>>>(tmp, gcur, row_start, dinv, es, n, e);
    k_gemm1<<<(n + 63) / 64, 256, 0, stream>>>(x, Wp, dinv, hw1, n);
    k_agg1<<<(n + 15) / 16, 256, 0, stream>>>(row_start, es, dinv, (const uint_t*)hw1, b1, W2, hw2, n);
    k_agg2<<<(n + 15) / 16, 256, 0, stream>>>(row_start, es, dinv, (const uint_t*)hw2, b2, out, n);
}

// Round 4
// 227.860 us; speedup vs baseline: 1.2355x; 1.0010x over previous
//
#include <hip/hip_runtime.h>
#include <hip/hip_bf16.h>

#define NNODES 100000
#define NEDGES 1600000
#define IN_CH 128
#define HID 64
#define NC 40
#define NPAD 100352   // NNODES padded to multiple of 256
#define NBUK 196      // ceil(100000 / 512) dst-buckets of 512 nodes
#define CAP 9216      // per-bucket tmp capacity (mean 8192, sigma ~90 -> 11 sigma)
#define BCHUNK 4096
#define NBIN 391      // ceil(NEDGES / BCHUNK)
#define HW2S 64       // hw2 row stride in ushorts (128 B line-aligned; 40 used)

typedef unsigned short ushort_t;
typedef unsigned int uint_t;
typedef __attribute__((ext_vector_type(8))) short short8;
typedef __attribute__((ext_vector_type(4))) float floatx4;

__device__ __forceinline__ ushort_t f2bf(float f) {
    union { float ff; unsigned int i; } t;
    t.ff = f;
    unsigned int r = t.i + 0x7fff + ((t.i >> 16) & 1);  // RNE
    return (ushort_t)(r >> 16);
}
// unpack packed bf16x2
__device__ __forceinline__ float2 unpk(uint_t p) {
    union { unsigned int i; float f; } a, b;
    a.i = p << 16;
    b.i = p & 0xffff0000u;
    return make_float2(a.f, b.f);
}
// acc += unpk(p), written as float2 math (packed-f32 friendly)
__device__ __forceinline__ void acc2(float2& a, uint_t p) {
    union { unsigned int i; float f; } lo, hi;
    lo.i = p << 16;
    hi.i = p & 0xffff0000u;
    a.x += lo.f;
    a.y += hi.f;
}

// ---- init: Wp swizzle (blocks 0..31) + gcur init + hw2 zero-sentinel (block 32) ----
__global__ __launch_bounds__(256) void k_init(
    const float* __restrict__ W1, ushort_t* __restrict__ Wp,
    int* __restrict__ gcur, ushort_t* __restrict__ hw2, int n)
{
    int b = blockIdx.x, t = threadIdx.x;
    if (b < 32) {
        int i = b * 256 + t;           // < 8192
        int j = i & 7;
        int m = (i >> 3) & 15;
        int ct = (i >> 7) & 3;
        int quad = (i >> 9) & 3;
        int kc = i >> 11;
        int k = kc * 32 + quad * 8 + j;
        int c = ct * 16 + m;
        Wp[i] = f2bf(W1[k * HID + c]);
    } else {
        if (t < NBUK) gcur[t] = t * CAP;
        if (t >= 224 && t < 224 + NC) hw2[(size_t)n * HW2S + (t - 224)] = 0;
    }
}

// ---- bin edges into bucket-major tmp; entry: src(17b) | local_d(9b)<<17 ----
__global__ __launch_bounds__(256) void k_bin0(
    const int* __restrict__ srcs, const int* __restrict__ dsts,
    int* __restrict__ gcur, uint_t* __restrict__ tmp, int e)
{
    __shared__ uint_t pk[BCHUNK];    // 16 KB
    __shared__ ushort_t bk[BCHUNK];  // 8 KB
    __shared__ int hist[NBUK];
    __shared__ int base[NBUK];
    int t = threadIdx.x;
    int begin = blockIdx.x * BCHUNK;
    int cnt = e - begin; if (cnt > BCHUNK) cnt = BCHUNK;

    for (int i = t; i < NBUK; i += 256) hist[i] = 0;
    __syncthreads();
    for (int j = t; j < cnt; j += 256) {
        int d = dsts[begin + j];
        int s = srcs[begin + j];
        int b = d >> 9;
        pk[j] = (uint_t)s | ((uint_t)(d & 511) << 17);
        bk[j] = (ushort_t)b;
        atomicAdd(&hist[b], 1);
    }
    __syncthreads();
    for (int i = t; i < NBUK; i += 256) {
        base[i] = atomicAdd(&gcur[i], hist[i]);  // reserve segment in bucket i
        hist[i] = 0;                             // reuse as local rank cursor
    }
    __syncthreads();
    for (int j = t; j < cnt; j += 256) {
        int b = bk[j];
        int r = atomicAdd(&hist[b], 1);
        int pos = base[b] + r;
        if (pos < (b + 1) * CAP) tmp[pos] = pk[j];  // burst writes; guard vs overflow
    }
}

// ---- merged sort: per-bucket count + scan + row_start/dinv + scatter to es ----
__global__ __launch_bounds__(256) void k_sort(
    const uint_t* __restrict__ tmp, const int* __restrict__ gcur,
    int* __restrict__ row_start, float* __restrict__ dinv,
    uint_t* __restrict__ es, int n, int e)
{
    __shared__ int cnt[512];
    __shared__ int sc[512];
    __shared__ int red[256];
    int t = threadIdx.x;
    int b = blockIdx.x;
    int d0 = b << 9;
    int total = gcur[b] - b * CAP;
    if (total > CAP) total = CAP;
    // gb = exclusive prefix over bucket totals
    int part = 0;
    for (int i = t; i < b; i += 256) part += gcur[i] - i * CAP;
    red[t] = part;
    cnt[t] = 0; cnt[t + 256] = 0;
    __syncthreads();
    for (int off = 128; off > 0; off >>= 1) {
        if (t < off) red[t] += red[t + off];
        __syncthreads();
    }
    int gb = red[0];
    // count per node
    const uint_t* seg = tmp + b * CAP;
    for (int j = t; j < total; j += 256)
        atomicAdd(&cnt[seg[j] >> 17], 1);
    __syncthreads();
    sc[t] = cnt[t]; sc[t + 256] = cnt[t + 256];
    __syncthreads();
    for (int off = 1; off < 512; off <<= 1) {
        int v0 = (t >= off) ? sc[t - off] : 0;
        int i1 = t + 256;
        int v1 = (i1 >= off) ? sc[i1 - off] : 0;
        __syncthreads();
        sc[t] += v0; sc[i1] += v1;
        __syncthreads();
    }
#pragma unroll
    for (int q = 0; q < 2; ++q) {
        int i = t + q * 256;
        int node = d0 + i;
        int start = gb + sc[i] - cnt[i];
        if (node < n) {
            row_start[node] = start;
            dinv[node] = rsqrtf((float)cnt[i] + 1.0f);
        }
        cnt[i] = start;   // reuse cnt as scatter cursor (own-thread overwrite)
    }
    __syncthreads();
    // scatter to final CSR order
    for (int j = t; j < total; j += 256) {
        uint_t p = seg[j];
        int ld = (int)(p >> 17);
        int pos = atomicAdd(&cnt[ld], 1);
        es[pos] = p & 0x1FFFFu;
    }
    if (b == NBUK - 1 && t == 0) row_start[n] = e;
}

// ---- GEMM1: hw1 = bf16(dinv * (x @ W1)) via MFMA; row n = zero sentinel ----
__global__ __launch_bounds__(256) void k_gemm1(
    const float* __restrict__ x, const ushort_t* __restrict__ Wp,
    const float* __restrict__ dinv, ushort_t* __restrict__ hw1, int n)
{
    int wave = threadIdx.x >> 6;
    int lane = threadIdx.x & 63;
    int m = lane & 15;
    int quad = lane >> 4;
    int row = blockIdx.x * 64 + wave * 16 + m;
    int rowc = row < n ? row : (n - 1);
    const float* xr = x + (size_t)rowc * IN_CH + quad * 8;

    floatx4 acc[4];
#pragma unroll
    for (int ct = 0; ct < 4; ++ct) acc[ct] = (floatx4){0.f, 0.f, 0.f, 0.f};

#pragma unroll
    for (int kc = 0; kc < 4; ++kc) {
        float4 xa = *(const float4*)(xr + kc * 32);
        float4 xb = *(const float4*)(xr + kc * 32 + 4);
        short8 a;
        a[0] = (short)f2bf(xa.x); a[1] = (short)f2bf(xa.y);
        a[2] = (short)f2bf(xa.z); a[3] = (short)f2bf(xa.w);
        a[4] = (short)f2bf(xb.x); a[5] = (short)f2bf(xb.y);
        a[6] = (short)f2bf(xb.z); a[7] = (short)f2bf(xb.w);
#pragma unroll
        for (int ct = 0; ct < 4; ++ct) {
            short8 b = *(const short8*)(Wp + ((((kc * 4 + quad) * 4 + ct) * 16 + m) << 3));
            acc[ct] = __builtin_amdgcn_mfma_f32_16x16x32_bf16(a, b, acc[ct], 0, 0, 0);
        }
    }
    int r0 = blockIdx.x * 64 + wave * 16 + quad * 4;
#pragma unroll
    for (int r = 0; r < 4; ++r) {
        int rr = r0 + r;
        if (rr < n) {
            float di = dinv[rr];
            ushort_t* o = hw1 + (size_t)rr * HID + m;
#pragma unroll
            for (int ct = 0; ct < 4; ++ct) o[ct * 16] = f2bf(acc[ct][r] * di);
        } else if (rr == n) {
            ushort_t* o = hw1 + (size_t)n * HID + m;
#pragma unroll
            for (int ct = 0; ct < 4; ++ct) o[ct * 16] = 0;
        }
    }
}

// ---- agg1 + fused GEMM2: one OCTET (8 lanes) per node ----
// Row = 64ch bf16 = 128 B = 8 lanes x dwordx4; one gather instruction fetches
// 8 rows (one per octet) -> 2x rows/instruction vs quarter-wave, 8 chains/wave.
// Sentinel row n is all-zero so padded window slots add exactly 0. All shfl
// source the own octet (uniformly active). Epilogue: wave's 8 h-rows -> LDS,
// then two 4-node quarter-wave passes compute h@W2 (same code as round 3,
// which measured 0 LDS bank conflicts). Same-wave produce/consume: no barrier.
__global__ __launch_bounds__(256) void k_agg1(
    const int* __restrict__ row_start, const uint_t* __restrict__ es,
    const float* __restrict__ dinv, const uint_t* __restrict__ hw1u,
    const float* __restrict__ b1, const float* __restrict__ W2,
    ushort_t* __restrict__ hw2, int n)
{
    __shared__ float wsm[HID * NC];   // 10 KB, W2 row-major [64][40]
    __shared__ float hsm[32][68];     // 32 nodes x 64ch (+pad)
    for (int i = threadIdx.x; i < HID * NC; i += 256) wsm[i] = W2[i];
    __syncthreads();

    int lane = threadIdx.x & 63;
    int obase = lane & 56;              // octet's first lane in the wave
    int ol = lane & 7;
    int slot = threadIdx.x >> 3;        // node slot within block (0..31)
    int node = blockIdx.x * 32 + slot;
    bool valid = node < n;
    int rs = valid ? row_start[node] : 0;
    int re = valid ? row_start[node + 1] : 0;
    float di = valid ? dinv[node] : 0.f;
    int selfrow = valid ? node : n;

    float2 c0, c1, c2, c3;
    {
        uint4 sp = *(const uint4*)(hw1u + (size_t)selfrow * 32 + ol * 4);
        c0 = unpk(sp.x); c1 = unpk(sp.y); c2 = unpk(sp.z); c3 = unpk(sp.w);
    }
    for (int base = rs; base < re; base += 16) {
        int i0 = base + ol, i1 = base + 8 + ol;
        int elA = (i0 < re) ? (int)es[i0] : n;   // pad -> zero sentinel
        int elB = (i1 < re) ? (int)es[i1] : n;
        int nw = re - base;                      // uniform per octet
        uint4 pA[8], pB[8];
#pragma unroll
        for (int b = 0; b < 8; ++b) {
            int s = __shfl(elA, obase + b);
            pA[b] = *(const uint4*)(hw1u + (size_t)s * 32 + ol * 4);
        }
        bool more = nw > 8;
        if (more) {
#pragma unroll
            for (int b = 0; b < 8; ++b) {
                int s = __shfl(elB, obase + b);
                pB[b] = *(const uint4*)(hw1u + (size_t)s * 32 + ol * 4);
            }
        }
#pragma unroll
        for (int b = 0; b < 8; ++b) {
            acc2(c0, pA[b].x); acc2(c1, pA[b].y);
            acc2(c2, pA[b].z); acc2(c3, pA[b].w);
        }
        if (more) {
#pragma unroll
            for (int b = 0; b < 8; ++b) {
                acc2(c0, pB[b].x); acc2(c1, pB[b].y);
                acc2(c2, pB[b].z); acc2(c3, pB[b].w);
            }
        }
    }
    // h = relu(agg*di + b1) -> LDS tile (8 ch per lane)
    {
        float4 bb0 = ((const float4*)b1)[ol * 2];
        float4 bb1 = ((const float4*)b1)[ol * 2 + 1];
        float4 h0, h1;
        h0.x = fmaxf(c0.x * di + bb0.x, 0.f);
        h0.y = fmaxf(c0.y * di + bb0.y, 0.f);
        h0.z = fmaxf(c1.x * di + bb0.z, 0.f);
        h0.w = fmaxf(c1.y * di + bb0.w, 0.f);
        h1.x = fmaxf(c2.x * di + bb1.x, 0.f);
        h1.y = fmaxf(c2.y * di + bb1.y, 0.f);
        h1.z = fmaxf(c3.x * di + bb1.z, 0.f);
        h1.w = fmaxf(c3.y * di + bb1.w, 0.f);
        *(float4*)&hsm[slot][ol * 8] = h0;
        *(float4*)&hsm[slot][ol * 8 + 4] = h1;
    }
    // fused GEMM2: two passes of 4-node quarter-wave dot over the wave's rows
    int w8 = (threadIdx.x >> 6) * 8;    // wave's first slot
    int qm = lane >> 4;                 // quarter 0..3
    int lq = lane & 15;
    int lw = (lq < 10) ? lq : 0;
    const float4* w4 = (const float4*)wsm;     // [64][10] float4
#pragma unroll
    for (int pass = 0; pass < 2; ++pass) {
        int slot2 = w8 + pass * 4 + qm;
        int node2 = blockIdx.x * 32 + slot2;
        float4 acc = make_float4(0.f, 0.f, 0.f, 0.f);
#pragma unroll 4
        for (int k4 = 0; k4 < 16; ++k4) {
            float4 hk = *(const float4*)&hsm[slot2][k4 * 4];
            float4 w0 = w4[(k4 * 4 + 0) * 10 + lw];
            float4 w1 = w4[(k4 * 4 + 1) * 10 + lw];
            float4 w2 = w4[(k4 * 4 + 2) * 10 + lw];
            float4 w3 = w4[(k4 * 4 + 3) * 10 + lw];
            acc.x += hk.x * w0.x + hk.y * w1.x + hk.z * w2.x + hk.w * w3.x;
            acc.y += hk.x * w0.y + hk.y * w1.y + hk.z * w2.y + hk.w * w3.y;
            acc.z += hk.x * w0.z + hk.y * w1.z + hk.z * w2.z + hk.w * w3.z;
            acc.w += hk.x * w0.w + hk.y * w1.w + hk.z * w2.w + hk.w * w3.w;
        }
        if (node2 < n && lq < 10) {
            float di2 = dinv[node2];
            uint2 st;
            st.x = (uint_t)f2bf(acc.x * di2) | ((uint_t)f2bf(acc.y * di2) << 16);
            st.y = (uint_t)f2bf(acc.z * di2) | ((uint_t)f2bf(acc.w * di2) << 16);
            *(uint2*)(hw2 + (size_t)node2 * HW2S + lq * 4) = st;
        }
    }
}

// ---- agg2: one OCTET per node; hw2 rows 128 B stride, data = 5 lanes x dwordx4 ----
// Lanes 5..7 clamp to lane-0's address (garbage acc, never stored).
__global__ __launch_bounds__(256) void k_agg2(
    const int* __restrict__ row_start, const uint_t* __restrict__ es,
    const float* __restrict__ dinv, const uint_t* __restrict__ hw2u,
    const float* __restrict__ b2, float* __restrict__ out, int n)
{
    int lane = threadIdx.x & 63;
    int obase = lane & 56;
    int ol = lane & 7;
    int lc = (ol < 5) ? ol : 0;         // clamped data-lane index
    int node = blockIdx.x * 32 + (threadIdx.x >> 3);
    bool valid = node < n;
    int rs = valid ? row_start[node] : 0;
    int re = valid ? row_start[node + 1] : 0;
    float di = valid ? dinv[node] : 0.f;
    int selfrow = valid ? node : n;

    float2 c0, c1, c2, c3;
    {
        uint4 sp = *(const uint4*)(hw2u + (size_t)selfrow * (HW2S / 2) + lc * 4);
        c0 = unpk(sp.x); c1 = unpk(sp.y); c2 = unpk(sp.z); c3 = unpk(sp.w);
    }
    for (int base = rs; base < re; base += 16) {
        int i0 = base + ol, i1 = base + 8 + ol;
        int elA = (i0 < re) ? (int)es[i0] : n;   // pad -> zero sentinel
        int elB = (i1 < re) ? (int)es[i1] : n;
        int nw = re - base;                      // uniform per octet
        uint4 pA[8], pB[8];
#pragma unroll
        for (int b = 0; b < 8; ++b) {
            int s = __shfl(elA, obase + b);
            pA[b] = *(const uint4*)(hw2u + (size_t)s * (HW2S / 2) + lc * 4);
        }
        bool more = nw > 8;
        if (more) {
#pragma unroll
            for (int b = 0; b < 8; ++b) {
                int s = __shfl(elB, obase + b);
                pB[b] = *(const uint4*)(hw2u + (size_t)s * (HW2S / 2) + lc * 4);
            }
        }
#pragma unroll
        for (int b = 0; b < 8; ++b) {
            acc2(c0, pA[b].x); acc2(c1, pA[b].y);
            acc2(c2, pA[b].z); acc2(c3, pA[b].w);
        }
        if (more) {
#pragma unroll
            for (int b = 0; b < 8; ++b) {
                acc2(c0, pB[b].x); acc2(c1, pB[b].y);
                acc2(c2, pB[b].z); acc2(c3, pB[b].w);
            }
        }
    }
    if (valid && ol < 5) {
        float4 bb0 = ((const float4*)b2)[ol * 2];
        float4 bb1 = ((const float4*)b2)[ol * 2 + 1];
        float4 o0, o1;
        o0.x = c0.x * di + bb0.x;
        o0.y = c0.y * di + bb0.y;
        o0.z = c1.x * di + bb0.z;
        o0.w = c1.y * di + bb0.w;
        o1.x = c2.x * di + bb1.x;
        o1.y = c2.y * di + bb1.y;
        o1.z = c3.x * di + bb1.z;
        o1.w = c3.y * di + bb1.w;
        float4* op = (float4*)(out + (size_t)node * 40 + ol * 8);
        op[0] = o0;
        op[1] = o1;
    }
}

extern "C" void kernel_launch(void* const* d_in, const int* in_sizes, int n_in,
                              void* d_out, int out_size, void* d_ws, size_t ws_size,
                              hipStream_t stream) {
    const float* x  = (const float*)d_in[0];   // f32 [N,128]
    const int* edge = (const int*)d_in[1];     // int32 [2,E]
    const float* W1 = (const float*)d_in[2];   // f32 [128,64]
    const float* b1 = (const float*)d_in[3];   // f32 [64]
    const float* W2 = (const float*)d_in[4];   // f32 [64,40]
    const float* b2 = (const float*)d_in[5];   // f32 [40]
    float* out      = (float*)d_out;           // f32 [N,40]

    const int n = in_sizes[0] / IN_CH;   // 100000
    const int e = in_sizes[1] / 2;       // 1600000
    const int* srcs = edge;
    const int* dsts = edge + e;

    // workspace layout (all segments 16B-aligned)
    int*      gcur      = (int*)d_ws;                       // 256
    int*      row_start = gcur + 256;                       // NPAD (needs n+1)
    float*    dinv      = (float*)(row_start + NPAD);       // NPAD
    uint_t*   tmp       = (uint_t*)(dinv + NPAD);           // NBUK*CAP packed 4B
    uint_t*   es        = tmp + (size_t)NBUK * CAP;         // NEDGES src-only 4B
    ushort_t* Wp        = (ushort_t*)(es + NEDGES);         // 8192 bf16
    ushort_t* hw1       = Wp + 8192;                        // (N+1)*64 bf16 (sentinel row n)
    ushort_t* hw2       = hw1 + (size_t)(NNODES + 1) * HID; // (N+1)*HW2S bf16 (40 used)

    k_init<<<33, 256, 0, stream>>>(W1, Wp, gcur, hw2, n);
    k_bin0<<<NBIN, 256, 0, stream>>>(srcs, dsts, gcur, tmp, e);
    k_sort<<<NBUK, 256, 0, stream>>>(tmp, gcur, row_start, dinv, es, n, e);
    k_gemm1<<<(n + 63) / 64, 256, 0, stream>>>(x, Wp, dinv, hw1, n);
    k_agg1<<<(n + 31) / 32, 256, 0, stream>>>(row_start, es, dinv, (const uint_t*)hw1, b1, W2, hw2, n);
    k_agg2<<<(n + 31) / 32, 256, 0, stream>>>(row_start, es, dinv, (const uint_t*)hw2, b2, out, n);
}